// Round 1
// baseline (105.906 us; speedup 1.0000x reference)
//
#include <hip/hip_runtime.h>

#define B_SZ 1024
#define DIN 1024
#define H_SZ 512
#define OUT_SZ 512
#define EPSF 1e-8f
#define KC 64

// ---------------- GEMM + bias + relu ----------------
// h[b][j] = relu(sum_k x[b][k] * W1[j][k] + b1[j])
// BM=64 (b), BN=32 (j), BK=16; 256 threads, 4x2 outputs per thread.
__global__ __launch_bounds__(256) void gemm_relu(const float* __restrict__ x,
                                                 const float* __restrict__ W1,
                                                 const float* __restrict__ b1,
                                                 float* __restrict__ h) {
    __shared__ float xs[16][68];   // k-major, padded: stride 68 dwords
    __shared__ float ws[16][36];
    const int b0 = blockIdx.x * 64;
    const int j0 = blockIdx.y * 32;
    const int t = threadIdx.x;
    const int tx = t & 15;   // b-group: rows tx*4 .. tx*4+3
    const int ty = t >> 4;   // j-group: cols ty*2 .. ty*2+1
    float acc[4][2] = {};
    for (int k0 = 0; k0 < DIN; k0 += 16) {
        // stage x tile: 64 rows x 16 k  (one float4 per thread)
        {
            const int row = t >> 2;         // 0..63
            const int kq = (t & 3) * 4;     // 0,4,8,12
            const float4 v = *reinterpret_cast<const float4*>(&x[(size_t)(b0 + row) * DIN + k0 + kq]);
            xs[kq + 0][row] = v.x; xs[kq + 1][row] = v.y;
            xs[kq + 2][row] = v.z; xs[kq + 3][row] = v.w;
        }
        // stage W1 tile: 32 rows x 16 k  (one float2 per thread)
        {
            const int row = t >> 3;         // 0..31
            const int kh = (t & 7) * 2;     // 0..14
            const float2 v = *reinterpret_cast<const float2*>(&W1[(size_t)(j0 + row) * DIN + k0 + kh]);
            ws[kh + 0][row] = v.x; ws[kh + 1][row] = v.y;
        }
        __syncthreads();
        #pragma unroll
        for (int kk = 0; kk < 16; ++kk) {
            const float4 a = *reinterpret_cast<const float4*>(&xs[kk][tx * 4]);
            const float w0 = ws[kk][ty * 2 + 0];
            const float w1 = ws[kk][ty * 2 + 1];
            acc[0][0] = fmaf(a.x, w0, acc[0][0]); acc[0][1] = fmaf(a.x, w1, acc[0][1]);
            acc[1][0] = fmaf(a.y, w0, acc[1][0]); acc[1][1] = fmaf(a.y, w1, acc[1][1]);
            acc[2][0] = fmaf(a.z, w0, acc[2][0]); acc[2][1] = fmaf(a.z, w1, acc[2][1]);
            acc[3][0] = fmaf(a.w, w0, acc[3][0]); acc[3][1] = fmaf(a.w, w1, acc[3][1]);
        }
        __syncthreads();
    }
    const float bias0 = b1[j0 + ty * 2 + 0];
    const float bias1 = b1[j0 + ty * 2 + 1];
    #pragma unroll
    for (int i = 0; i < 4; ++i) {
        const int bb = b0 + tx * 4 + i;
        float2 o;
        o.x = fmaxf(acc[i][0] + bias0, 0.0f);
        o.y = fmaxf(acc[i][1] + bias1, 0.0f);
        *reinterpret_cast<float2*>(&h[(size_t)bb * H_SZ + j0 + ty * 2]) = o;
    }
}

// ---------------- Canberra distance + reciprocal ----------------
// out[b][o] = 1 / clip( eps + sum_k |h[b,k]-Wd[o,k]| / max(|h[b,k]|+|Wd[o,k]|, eps), eps, 1e6 )
// h >= 0 (post-relu) so |h| = h.
// Tile: 32 b x 32 o per block, 256 threads: each thread 1 b-row x 4 o-rows (o strided by 8).
__global__ __launch_bounds__(256) void canberra(const float* __restrict__ h,
                                                const float* __restrict__ Wd,
                                                float* __restrict__ out) {
    __shared__ float hs[32][KC + 4];    // stride 68 dwords, rows 16B-aligned
    __shared__ float wds[32][KC + 4];
    const int b0 = blockIdx.x * 32;
    const int o0 = blockIdx.y * 32;
    const int t = threadIdx.x;
    const int oi = t & 7;    // o = o0 + oi + 8*j
    const int bi = t >> 3;   // b = b0 + bi
    float acc[4] = {};
    for (int k0 = 0; k0 < H_SZ; k0 += KC) {
        // stage: 32 x KC floats each = 512 float4 = 2 per thread
        #pragma unroll
        for (int r = 0; r < 2; ++r) {
            const int f = t + r * 256;      // 0..511
            const int row = f >> 4;         // 0..31
            const int kq = (f & 15) * 4;    // 0..60
            *reinterpret_cast<float4*>(&hs[row][kq]) =
                *reinterpret_cast<const float4*>(&h[(size_t)(b0 + row) * H_SZ + k0 + kq]);
            *reinterpret_cast<float4*>(&wds[row][kq]) =
                *reinterpret_cast<const float4*>(&Wd[(size_t)(o0 + row) * H_SZ + k0 + kq]);
        }
        __syncthreads();
        #pragma unroll
        for (int kk = 0; kk < KC; kk += 4) {
            const float4 hv = *reinterpret_cast<const float4*>(&hs[bi][kk]);
            #pragma unroll
            for (int j = 0; j < 4; ++j) {
                const float4 wv = *reinterpret_cast<const float4*>(&wds[oi + 8 * j][kk]);
                float s0 = fmaxf(hv.x + fabsf(wv.x), EPSF);
                float s1 = fmaxf(hv.y + fabsf(wv.y), EPSF);
                float s2 = fmaxf(hv.z + fabsf(wv.z), EPSF);
                float s3 = fmaxf(hv.w + fabsf(wv.w), EPSF);
                acc[j] = fmaf(fabsf(hv.x - wv.x), __builtin_amdgcn_rcpf(s0), acc[j]);
                acc[j] = fmaf(fabsf(hv.y - wv.y), __builtin_amdgcn_rcpf(s1), acc[j]);
                acc[j] = fmaf(fabsf(hv.z - wv.z), __builtin_amdgcn_rcpf(s2), acc[j]);
                acc[j] = fmaf(fabsf(hv.w - wv.w), __builtin_amdgcn_rcpf(s3), acc[j]);
            }
        }
        __syncthreads();
    }
    #pragma unroll
    for (int j = 0; j < 4; ++j) {
        float d = acc[j] + EPSF;
        d = fminf(fmaxf(d, EPSF), 1000000.0f);
        out[(size_t)(b0 + bi) * OUT_SZ + o0 + oi + 8 * j] = 1.0f / d;  // exact div, epilogue only
    }
}

extern "C" void kernel_launch(void* const* d_in, const int* in_sizes, int n_in,
                              void* d_out, int out_size, void* d_ws, size_t ws_size,
                              hipStream_t stream) {
    const float* x  = (const float*)d_in[0];
    const float* W1 = (const float*)d_in[1];
    const float* b1 = (const float*)d_in[2];
    const float* Wd = (const float*)d_in[3];
    float* out = (float*)d_out;
    float* h   = (float*)d_ws;   // needs 1024*512*4 = 2 MB of scratch

    gemm_relu<<<dim3(16, 16), 256, 0, stream>>>(x, W1, b1, h);
    canberra<<<dim3(32, 16), 256, 0, stream>>>(h, Wd, out);
}

// Round 2
// 70.592 us; speedup vs baseline: 1.5003x; 1.5003x over previous
//
#include <hip/hip_runtime.h>

#define B_SZ 1024
#define DIN 1024
#define H_SZ 512
#define OUT_SZ 512
#define EPSF 1e-8f
#define KC 64

typedef __attribute__((ext_vector_type(8))) short short8v;   // 8 bf16 = 4 VGPRs
typedef __attribute__((ext_vector_type(4))) float f32x4;

// fp32 -> bf16 (RNE)
static __device__ inline unsigned short f2bf(float f) {
    unsigned u = __float_as_uint(f);
    u = u + 0x7FFFu + ((u >> 16) & 1u);
    return (unsigned short)(u >> 16);
}

// ---------------- GEMM (bf16 MFMA) + bias + relu ----------------
// h[b][j] = relu(sum_k x[b][k]*W1[j][k] + b1[j]);  x,W1 fp32 in, converted on stage.
// BM=64, BN=32, BK=32; 256 threads (4 waves); wave -> 32x16 quadrant via 2x mfma 16x16x32.
__global__ __launch_bounds__(256) void gemm_mfma(const float* __restrict__ x,
                                                 const float* __restrict__ W1,
                                                 const float* __restrict__ b1,
                                                 float* __restrict__ h) {
    __shared__ unsigned short As[64][40];   // [m][k], stride 40 bf16 = 80 B (pad kills 8-way conflicts)
    __shared__ unsigned short Bs[32][40];   // [n][k]
    const int t = threadIdx.x;
    const int b0 = blockIdx.x * 64;
    const int j0 = blockIdx.y * 32;
    const int w  = t >> 6;                // wave 0..3
    const int l  = t & 63;
    const int m0 = (w >> 1) * 32;         // 0 / 32
    const int n0 = (w & 1) * 16;          // 0 / 16
    const int lr = l & 15;
    const int lk = (l >> 4) * 8;          // k-offset of this lane's 8 contiguous bf16

    // staging assignment
    const int ar = t >> 2;                // 0..63
    const int ak = (t & 3) * 8;           // 0,8,16,24
    const int br = t >> 3;                // 0..31
    const int bk = (t & 7) * 4;           // 0..28

    f32x4 acc[2] = {{0.f,0.f,0.f,0.f},{0.f,0.f,0.f,0.f}};

    const float* xrow = &x[(size_t)(b0 + ar) * DIN + ak];
    const float* wrow = &W1[(size_t)(j0 + br) * DIN + bk];
    float4 pa0 = *reinterpret_cast<const float4*>(xrow);
    float4 pa1 = *reinterpret_cast<const float4*>(xrow + 4);
    float4 pb  = *reinterpret_cast<const float4*>(wrow);

    for (int k0 = 0; k0 < DIN; k0 += 32) {
        short8v av;
        av[0] = (short)f2bf(pa0.x); av[1] = (short)f2bf(pa0.y);
        av[2] = (short)f2bf(pa0.z); av[3] = (short)f2bf(pa0.w);
        av[4] = (short)f2bf(pa1.x); av[5] = (short)f2bf(pa1.y);
        av[6] = (short)f2bf(pa1.z); av[7] = (short)f2bf(pa1.w);
        ushort4 bv = make_ushort4(f2bf(pb.x), f2bf(pb.y), f2bf(pb.z), f2bf(pb.w));
        __syncthreads();   // previous iter's fragment reads done
        *reinterpret_cast<short8v*>(&As[ar][ak]) = av;
        *reinterpret_cast<ushort4*>(&Bs[br][bk]) = bv;
        __syncthreads();
        if (k0 + 32 < DIN) {  // prefetch next tile while mfma runs
            pa0 = *reinterpret_cast<const float4*>(xrow + k0 + 32);
            pa1 = *reinterpret_cast<const float4*>(xrow + k0 + 36);
            pb  = *reinterpret_cast<const float4*>(wrow + k0 + 32);
        }
        const short8v af0 = *reinterpret_cast<const short8v*>(&As[m0 + lr][lk]);
        const short8v af1 = *reinterpret_cast<const short8v*>(&As[m0 + 16 + lr][lk]);
        const short8v bf  = *reinterpret_cast<const short8v*>(&Bs[n0 + lr][lk]);
        acc[0] = __builtin_amdgcn_mfma_f32_16x16x32_bf16(af0, bf, acc[0], 0, 0, 0);
        acc[1] = __builtin_amdgcn_mfma_f32_16x16x32_bf16(af1, bf, acc[1], 0, 0, 0);
    }

    // C/D layout (m89-verified): col = lane&15, row = (lane>>4)*4 + reg
    const int col = j0 + n0 + lr;
    const float bias = b1[col];
    #pragma unroll
    for (int mi = 0; mi < 2; ++mi) {
        #pragma unroll
        for (int r = 0; r < 4; ++r) {
            const int m = b0 + m0 + mi * 16 + (l >> 4) * 4 + r;
            h[(size_t)m * H_SZ + col] = fmaxf(acc[mi][r] + bias, 0.0f);
        }
    }
}

// ---------------- Canberra + reciprocal (div-free inner loop) ----------------
// term: w<0 -> |h-w|/(h+|w|); h>=0. s=max(h+|w|,eps); rcp via magic seed + 1 Newton.
// Tile 32b x 32o, 512 threads, each thread 1 b-row x 2 o-rows. Grid 512 = 2 blk/CU = 16 waves/CU.
#define CANB(hc, wc, a) do {                                         \
    float s_ = fmaxf((hc) + fabsf(wc), EPSF);                        \
    float y_ = __uint_as_float(0x7EF127EAu - __float_as_uint(s_));   \
    y_ = y_ * fmaf(-s_, y_, 2.0f);                                   \
    (a) = fmaf(fabsf((hc) - (wc)), y_, (a));                         \
} while (0)

__global__ __launch_bounds__(512) void canberra2(const float* __restrict__ h,
                                                 const float* __restrict__ Wd,
                                                 float* __restrict__ out) {
    __shared__ float hs[32][KC + 4];     // stride 68 dwords: 16B-aligned rows, 2-way-max banks
    __shared__ float wds[32][KC + 4];
    const int t = threadIdx.x;
    const int b0 = blockIdx.x * 32;
    const int o0 = blockIdx.y * 32;
    const int bi = t >> 4;               // 0..31
    const int oj = t & 15;               // outputs o0+oj, o0+oj+16
    const int srow = t >> 4;
    const int skq  = (t & 15) * 4;

    float acc[2][4] = {};

    const float* hrow = &h[(size_t)(b0 + srow) * H_SZ + skq];
    const float* wrow = &Wd[(size_t)(o0 + srow) * H_SZ + skq];
    float4 ph = *reinterpret_cast<const float4*>(hrow);
    float4 pw = *reinterpret_cast<const float4*>(wrow);

    for (int k0 = 0; k0 < H_SZ; k0 += KC) {
        __syncthreads();
        *reinterpret_cast<float4*>(&hs[srow][skq])  = ph;
        *reinterpret_cast<float4*>(&wds[srow][skq]) = pw;
        __syncthreads();
        if (k0 + KC < H_SZ) {            // prefetch next chunk into regs
            ph = *reinterpret_cast<const float4*>(hrow + k0 + KC);
            pw = *reinterpret_cast<const float4*>(wrow + k0 + KC);
        }
        #pragma unroll
        for (int kk = 0; kk < KC; kk += 4) {
            const float4 hv = *reinterpret_cast<const float4*>(&hs[bi][kk]);
            #pragma unroll
            for (int j = 0; j < 2; ++j) {
                const float4 wv = *reinterpret_cast<const float4*>(&wds[oj + 16 * j][kk]);
                CANB(hv.x, wv.x, acc[j][0]);
                CANB(hv.y, wv.y, acc[j][1]);
                CANB(hv.z, wv.z, acc[j][2]);
                CANB(hv.w, wv.w, acc[j][3]);
            }
        }
    }
    #pragma unroll
    for (int j = 0; j < 2; ++j) {
        float d = (acc[j][0] + acc[j][1]) + (acc[j][2] + acc[j][3]) + EPSF;
        d = fminf(fmaxf(d, EPSF), 1000000.0f);
        out[(size_t)(b0 + bi) * OUT_SZ + o0 + oj + 16 * j] = 1.0f / d;  // exact div, epilogue only
    }
}

extern "C" void kernel_launch(void* const* d_in, const int* in_sizes, int n_in,
                              void* d_out, int out_size, void* d_ws, size_t ws_size,
                              hipStream_t stream) {
    const float* x  = (const float*)d_in[0];
    const float* W1 = (const float*)d_in[1];
    const float* b1 = (const float*)d_in[2];
    const float* Wd = (const float*)d_in[3];
    float* out = (float*)d_out;
    float* h   = (float*)d_ws;   // 1024*512*4 = 2 MB scratch

    gemm_mfma<<<dim3(16, 16), 256, 0, stream>>>(x, W1, b1, h);
    canberra2<<<dim3(32, 16), 512, 0, stream>>>(h, Wd, out);
}

// Round 3
// 52.357 us; speedup vs baseline: 2.0228x; 1.3483x over previous
//
#include <hip/hip_runtime.h>
#include <hip/hip_fp16.h>

#define B_SZ 1024
#define DIN 1024
#define H_SZ 512
#define OUT_SZ 512
#define EPSF 1e-8f

typedef __attribute__((ext_vector_type(8))) short short8v;   // 8 bf16 = 4 VGPRs
typedef __attribute__((ext_vector_type(4))) float f32x4;
typedef _Float16 half2v __attribute__((ext_vector_type(2)));

// fp32 -> bf16 (RNE)
static __device__ inline unsigned short f2bf(float f) {
    unsigned u = __float_as_uint(f);
    u = u + 0x7FFFu + ((u >> 16) & 1u);
    return (unsigned short)(u >> 16);
}

// ---------------- Wd preprocess: w' = relu(Wd) as fp16 ----------------
__global__ __launch_bounds__(256) void relu_cvt(const float* __restrict__ Wd,
                                                unsigned short* __restrict__ wh) {
    const int i = (blockIdx.x * 256 + threadIdx.x) * 4;
    const float4 v = *reinterpret_cast<const float4*>(&Wd[i]);
    // guarantee +0 for non-positive w (no -0 bits: magic-sub borrow safety)
    const float a0 = v.x > 0.f ? v.x : 0.f;
    const float a1 = v.y > 0.f ? v.y : 0.f;
    const float a2 = v.z > 0.f ? v.z : 0.f;
    const float a3 = v.w > 0.f ? v.w : 0.f;
    const unsigned u0 = __half_as_ushort(__float2half(a0));
    const unsigned u1 = __half_as_ushort(__float2half(a1));
    const unsigned u2 = __half_as_ushort(__float2half(a2));
    const unsigned u3 = __half_as_ushort(__float2half(a3));
    uint2 o;
    o.x = u0 | (u1 << 16);
    o.y = u2 | (u3 << 16);
    *reinterpret_cast<uint2*>(&reinterpret_cast<unsigned*>(wh)[i >> 1]) = o;
}

// ---------------- GEMM (bf16 MFMA) + bias + relu -> fp16 h ----------------
__global__ __launch_bounds__(256) void gemm_mfma(const float* __restrict__ x,
                                                 const float* __restrict__ W1,
                                                 const float* __restrict__ b1,
                                                 unsigned short* __restrict__ hh) {
    __shared__ unsigned short As[64][40];
    __shared__ unsigned short Bs[32][40];
    const int t = threadIdx.x;
    const int b0 = blockIdx.x * 64;
    const int j0 = blockIdx.y * 32;
    const int w  = t >> 6;
    const int l  = t & 63;
    const int m0 = (w >> 1) * 32;
    const int n0 = (w & 1) * 16;
    const int lr = l & 15;
    const int lk = (l >> 4) * 8;

    const int ar = t >> 2;
    const int ak = (t & 3) * 8;
    const int br = t >> 3;
    const int bk = (t & 7) * 4;

    f32x4 acc[2] = {{0.f,0.f,0.f,0.f},{0.f,0.f,0.f,0.f}};

    const float* xrow = &x[(size_t)(b0 + ar) * DIN + ak];
    const float* wrow = &W1[(size_t)(j0 + br) * DIN + bk];
    float4 pa0 = *reinterpret_cast<const float4*>(xrow);
    float4 pa1 = *reinterpret_cast<const float4*>(xrow + 4);
    float4 pb  = *reinterpret_cast<const float4*>(wrow);

    for (int k0 = 0; k0 < DIN; k0 += 32) {
        short8v av;
        av[0] = (short)f2bf(pa0.x); av[1] = (short)f2bf(pa0.y);
        av[2] = (short)f2bf(pa0.z); av[3] = (short)f2bf(pa0.w);
        av[4] = (short)f2bf(pa1.x); av[5] = (short)f2bf(pa1.y);
        av[6] = (short)f2bf(pa1.z); av[7] = (short)f2bf(pa1.w);
        ushort4 bv = make_ushort4(f2bf(pb.x), f2bf(pb.y), f2bf(pb.z), f2bf(pb.w));
        __syncthreads();
        *reinterpret_cast<short8v*>(&As[ar][ak]) = av;
        *reinterpret_cast<ushort4*>(&Bs[br][bk]) = bv;
        __syncthreads();
        if (k0 + 32 < DIN) {
            pa0 = *reinterpret_cast<const float4*>(xrow + k0 + 32);
            pa1 = *reinterpret_cast<const float4*>(xrow + k0 + 36);
            pb  = *reinterpret_cast<const float4*>(wrow + k0 + 32);
        }
        const short8v af0 = *reinterpret_cast<const short8v*>(&As[m0 + lr][lk]);
        const short8v af1 = *reinterpret_cast<const short8v*>(&As[m0 + 16 + lr][lk]);
        const short8v bf  = *reinterpret_cast<const short8v*>(&Bs[n0 + lr][lk]);
        acc[0] = __builtin_amdgcn_mfma_f32_16x16x32_bf16(af0, bf, acc[0], 0, 0, 0);
        acc[1] = __builtin_amdgcn_mfma_f32_16x16x32_bf16(af1, bf, acc[1], 0, 0, 0);
    }

    // C/D layout: col = lane&15, row = (lane>>4)*4 + reg
    const int col = j0 + n0 + lr;
    const float bias = b1[col];
    #pragma unroll
    for (int mi = 0; mi < 2; ++mi) {
        #pragma unroll
        for (int r = 0; r < 4; ++r) {
            const int m = b0 + m0 + mi * 16 + (l >> 4) * 4 + r;
            hh[(size_t)m * H_SZ + col] =
                __half_as_ushort(__float2half(fmaxf(acc[mi][r] + bias, 0.0f)));
        }
    }
}

// ---------------- Canberra via identity: dist = 512 - 2*sum(min(h,w')/(h+w')) ----------------
// Packed fp16: 6 VALU per 2 terms. Magic-NR rcp (0x7784), no borrow (s<=11),
// no inf (seed(0)=30784, *2=61568 < 65504), min=0 kills degenerate terms.
static __device__ inline void canb2(unsigned hu, unsigned wu, half2v& a) {
    const half2v h2 = __builtin_bit_cast(half2v, hu);
    const half2v w2 = __builtin_bit_cast(half2v, wu);
    const half2v mn = __builtin_elementwise_min(h2, w2);
    const half2v sm = h2 + w2;
    half2v y = __builtin_bit_cast(half2v, 0x77847784u - __builtin_bit_cast(unsigned, sm));
    const half2v two = {(_Float16)2.0f, (_Float16)2.0f};
    y = y * (two - sm * y);          // 1 Newton step
    a = mn * y + a;                  // pk_fma accumulate
}

// Tile 32b x 32o, 1024 threads, 4-way k-split (128 k each), 2b x 2o per thread.
__global__ __launch_bounds__(1024) void canberra3(const unsigned short* __restrict__ hh,
                                                  const unsigned short* __restrict__ wh,
                                                  float* __restrict__ out) {
    __shared__ unsigned hs[4][32][68];    // stride 68 uints: 16B-aligned rows, h-read banks {0,8,16,24}
    __shared__ unsigned ws_[4][32][66];   // stride 66 uints: b64 reads, 2-way banks (free)
    const int t = threadIdx.x;
    const int b0 = blockIdx.x * 32;
    const int o0 = blockIdx.y * 32;
    const unsigned* hu = reinterpret_cast<const unsigned*>(hh);
    const unsigned* wu = reinterpret_cast<const unsigned*>(wh);

    // stage all 512 k at once: 2048 uint4 slots per array, 2 per thread
    #pragma unroll
    for (int r = 0; r < 2; ++r) {
        const int s = t + r * 1024;
        const int row = s >> 6;          // 0..31
        const int c16 = s & 63;          // uint4 col 0..63 (covers 256 uints = 512 k)
        const int ksc = c16 >> 4;
        const int c4 = c16 & 15;
        const uint4 hv = *reinterpret_cast<const uint4*>(&hu[(size_t)(b0 + row) * 256 + c16 * 4]);
        const uint4 wv = *reinterpret_cast<const uint4*>(&wu[(size_t)(o0 + row) * 256 + c16 * 4]);
        *reinterpret_cast<uint4*>(&hs[ksc][row][c4 * 4]) = hv;
        *reinterpret_cast<uint2*>(&ws_[ksc][row][c4 * 4])     = make_uint2(wv.x, wv.y);
        *reinterpret_cast<uint2*>(&ws_[ksc][row][c4 * 4 + 2]) = make_uint2(wv.z, wv.w);
    }
    __syncthreads();

    const int ks = t >> 8;               // wave-uniform k-quarter
    const int tid2 = t & 255;
    const int bi = (tid2 >> 4) * 2;
    const int oj = (tid2 & 15) * 2;

    half2v a00 = {}, a01 = {}, a10 = {}, a11 = {};
    #pragma unroll 4
    for (int g = 0; g < 16; ++g) {
        const uint4 ha  = *reinterpret_cast<const uint4*>(&hs[ks][bi][g * 4]);
        const uint4 hb  = *reinterpret_cast<const uint4*>(&hs[ks][bi + 1][g * 4]);
        const uint2 wa0 = *reinterpret_cast<const uint2*>(&ws_[ks][oj][g * 4]);
        const uint2 wa1 = *reinterpret_cast<const uint2*>(&ws_[ks][oj][g * 4 + 2]);
        const uint2 wb0 = *reinterpret_cast<const uint2*>(&ws_[ks][oj + 1][g * 4]);
        const uint2 wb1 = *reinterpret_cast<const uint2*>(&ws_[ks][oj + 1][g * 4 + 2]);
        canb2(ha.x, wa0.x, a00); canb2(ha.x, wb0.x, a01);
        canb2(hb.x, wa0.x, a10); canb2(hb.x, wb0.x, a11);
        canb2(ha.y, wa0.y, a00); canb2(ha.y, wb0.y, a01);
        canb2(hb.y, wa0.y, a10); canb2(hb.y, wb0.y, a11);
        canb2(ha.z, wa1.x, a00); canb2(ha.z, wb1.x, a01);
        canb2(hb.z, wa1.x, a10); canb2(hb.z, wb1.x, a11);
        canb2(ha.w, wa1.y, a00); canb2(ha.w, wb1.y, a01);
        canb2(hb.w, wa1.y, a10); canb2(hb.w, wb1.y, a11);
    }

    // reduce the 4 k-quarters via LDS (reuse hs after barrier)
    float p00 = (float)a00.x + (float)a00.y;
    float p01 = (float)a01.x + (float)a01.y;
    float p10 = (float)a10.x + (float)a10.y;
    float p11 = (float)a11.x + (float)a11.y;

    __syncthreads();                     // all LDS reads complete; hs reusable
    float* red = reinterpret_cast<float*>(&hs[0][0][0]);   // [3][256][4] floats = 12KB
    if (ks > 0) {
        float* rp = &red[((ks - 1) * 256 + tid2) * 4];
        rp[0] = p00; rp[1] = p01; rp[2] = p10; rp[3] = p11;
    }
    __syncthreads();
    if (ks == 0) {
        float s00 = p00, s01 = p01, s10 = p10, s11 = p11;
        #pragma unroll
        for (int p = 0; p < 3; ++p) {
            const float* rp = &red[(p * 256 + tid2) * 4];
            s00 += rp[0]; s01 += rp[1]; s10 += rp[2]; s11 += rp[3];
        }
        const float S[2][2] = {{s00, s01}, {s10, s11}};
        #pragma unroll
        for (int i = 0; i < 2; ++i) {
            #pragma unroll
            for (int j = 0; j < 2; ++j) {
                float d = (float)H_SZ - 2.0f * S[i][j] + EPSF;
                d = fminf(fmaxf(d, EPSF), 1000000.0f);
                out[(size_t)(b0 + bi + i) * OUT_SZ + o0 + oj + j] = 1.0f / d;
            }
        }
    }
}

extern "C" void kernel_launch(void* const* d_in, const int* in_sizes, int n_in,
                              void* d_out, int out_size, void* d_ws, size_t ws_size,
                              hipStream_t stream) {
    const float* x  = (const float*)d_in[0];
    const float* W1 = (const float*)d_in[1];
    const float* b1 = (const float*)d_in[2];
    const float* Wd = (const float*)d_in[3];
    float* out = (float*)d_out;
    unsigned short* hh = (unsigned short*)d_ws;                          // 1 MB fp16 h
    unsigned short* wh = (unsigned short*)((char*)d_ws + (1u << 20));    // 0.5 MB fp16 relu(Wd)

    relu_cvt<<<256, 256, 0, stream>>>(Wd, wh);
    gemm_mfma<<<dim3(16, 16), 256, 0, stream>>>(x, W1, b1, hh);
    canberra3<<<dim3(32, 16), 1024, 0, stream>>>(hh, wh, out);
}

// Round 5
// 43.706 us; speedup vs baseline: 2.4232x; 1.1979x over previous
//
#include <hip/hip_runtime.h>
#include <hip/hip_fp16.h>

#define DIN 1024
#define H_SZ 512
#define OUT_SZ 512
#define EPSF 1e-8f

typedef __attribute__((ext_vector_type(8))) short short8v;   // 8 bf16 = 4 VGPRs
typedef __attribute__((ext_vector_type(4))) float f32x4;
typedef _Float16 half2v __attribute__((ext_vector_type(2)));

// fp32 -> bf16 (RNE)
static __device__ inline unsigned short f2bf(float f) {
    unsigned u = __float_as_uint(f);
    u = u + 0x7FFFu + ((u >> 16) & 1u);
    return (unsigned short)(u >> 16);
}

// ---------------- GEMM (bf16 MFMA) + bias + relu -> fp16 h; also relu+cvt Wd -> fp16 ----------------
// Tile 32x32, BK=64, LDS double-buffer (1 barrier/iter), 256 thr (4 waves, each a 16x16 quadrant).
// 512 blocks = 2/CU for cross-block latency overlap.
__global__ __launch_bounds__(256, 4) void gemm_mfma(const float* __restrict__ x,
                                                    const float* __restrict__ W1,
                                                    const float* __restrict__ b1,
                                                    const float* __restrict__ Wd,
                                                    unsigned short* __restrict__ hh,
                                                    unsigned short* __restrict__ wh) {
    __shared__ unsigned short As[2][2][32][40];   // [buf][khalf][m][k0..31], stride 40 (proven bank layout)
    __shared__ unsigned short Bs[2][2][32][40];
    const int t = threadIdx.x;
    const int b0 = blockIdx.x * 32;
    const int j0 = blockIdx.y * 32;

    // folded Wd preprocess: w' = fp16(relu(Wd)), 512 elems per block, 2 per thread
    {
        const int flat = blockIdx.y * 32 + blockIdx.x;      // grid (32,16)
        const int i = flat * 512 + t * 2;
        const float2 v = *reinterpret_cast<const float2*>(&Wd[i]);
        const float a0 = v.x > 0.f ? v.x : 0.f;             // +0 only (no -0 bits)
        const float a1 = v.y > 0.f ? v.y : 0.f;
        const unsigned u = (unsigned)__half_as_ushort(__float2half(a0)) |
                           ((unsigned)__half_as_ushort(__float2half(a1)) << 16);
        reinterpret_cast<unsigned*>(wh)[i >> 1] = u;
    }

    const int w  = t >> 6;                 // wave 0..3
    const int l  = t & 63;
    const int m0 = (w >> 1) * 16;
    const int n0 = (w & 1) * 16;
    const int lr = l & 15;
    const int lk = (l >> 4) * 8;

    const int ar = t >> 3;                 // 0..31
    const int ak = (t & 7) * 8;            // 0..56
    const int kh = ak >> 5;                // 0/1
    const int ko = ak & 31;

    f32x4 acc = {0.f, 0.f, 0.f, 0.f};

    const float* xrow = &x[(size_t)(b0 + ar) * DIN + ak];
    const float* wrow = &W1[(size_t)(j0 + ar) * DIN + ak];
    float4 pa0 = *reinterpret_cast<const float4*>(xrow);
    float4 pa1 = *reinterpret_cast<const float4*>(xrow + 4);
    float4 pb0 = *reinterpret_cast<const float4*>(wrow);
    float4 pb1 = *reinterpret_cast<const float4*>(wrow + 4);

    for (int k0 = 0; k0 < DIN; k0 += 64) {
        const int buf = (k0 >> 6) & 1;
        short8v av, bv;
        av[0] = (short)f2bf(pa0.x); av[1] = (short)f2bf(pa0.y);
        av[2] = (short)f2bf(pa0.z); av[3] = (short)f2bf(pa0.w);
        av[4] = (short)f2bf(pa1.x); av[5] = (short)f2bf(pa1.y);
        av[6] = (short)f2bf(pa1.z); av[7] = (short)f2bf(pa1.w);
        bv[0] = (short)f2bf(pb0.x); bv[1] = (short)f2bf(pb0.y);
        bv[2] = (short)f2bf(pb0.z); bv[3] = (short)f2bf(pb0.w);
        bv[4] = (short)f2bf(pb1.x); bv[5] = (short)f2bf(pb1.y);
        bv[6] = (short)f2bf(pb1.z); bv[7] = (short)f2bf(pb1.w);
        *reinterpret_cast<short8v*>(&As[buf][kh][ar][ko]) = av;
        *reinterpret_cast<short8v*>(&Bs[buf][kh][ar][ko]) = bv;
        __syncthreads();   // writes of buf visible; buf^1's last reads were 2 syncs back -> safe
        if (k0 + 64 < DIN) {
            pa0 = *reinterpret_cast<const float4*>(xrow + k0 + 64);
            pa1 = *reinterpret_cast<const float4*>(xrow + k0 + 68);
            pb0 = *reinterpret_cast<const float4*>(wrow + k0 + 64);
            pb1 = *reinterpret_cast<const float4*>(wrow + k0 + 68);
        }
        #pragma unroll
        for (int s = 0; s < 2; ++s) {
            const short8v af = *reinterpret_cast<const short8v*>(&As[buf][s][m0 + lr][lk]);
            const short8v bf = *reinterpret_cast<const short8v*>(&Bs[buf][s][n0 + lr][lk]);
            acc = __builtin_amdgcn_mfma_f32_16x16x32_bf16(af, bf, acc, 0, 0, 0);
        }
    }

    // C/D layout (m89-verified): col = lane&15, row = (lane>>4)*4 + reg
    const int col = j0 + n0 + lr;
    const float bias = b1[col];
    #pragma unroll
    for (int r = 0; r < 4; ++r) {
        const int m = b0 + m0 + (l >> 4) * 4 + r;
        hh[(size_t)m * H_SZ + col] =
            __half_as_ushort(__float2half(fmaxf(acc[r] + bias, 0.0f)));
    }
}

// ---------------- Canberra: dist = 512 - 2*sum(min(h,w')/(h+w')),  sim = 1/dist ----------------
// Packed fp16 (round-3-proven formulation): 6 v_pk ops per 2 terms.
// Magic-NR rcp (0x7784 seed + 1 Newton): no borrow across halves (s small), no inf,
// min=0 kills degenerate terms. Passed at absmax 1.5e-5 in round 3.
static __device__ inline void canb2(unsigned hu, unsigned wu, half2v& a) {
    const half2v h2 = __builtin_bit_cast(half2v, hu);
    const half2v w2 = __builtin_bit_cast(half2v, wu);
    const half2v mn = __builtin_elementwise_min(h2, w2);
    const half2v sm = h2 + w2;
    half2v y = __builtin_bit_cast(half2v, 0x77847784u - __builtin_bit_cast(unsigned, sm));
    const half2v two = {(_Float16)2.0f, (_Float16)2.0f};
    y = y * (two - sm * y);          // 1 Newton step
    a = mn * y + a;                  // pk_fma accumulate
}

// Block: 512 thr, out-tile 32b x 32o, k-split 4 (128 k each).
// Thread (ks, ts): b-rows {bi+8c, c<4}, o-rows {oj+16d, d<2} -> 4x2 register tile.
// All LDS reads are b128; stride 260 uints -> bank = 4*row mod 32 -> broadcast/2-way (free).
__global__ __launch_bounds__(512, 4) void canberra4(const unsigned short* __restrict__ hh,
                                                    const unsigned short* __restrict__ wh,
                                                    float* __restrict__ out) {
    __shared__ unsigned hs[32][260];    // 32 rows x 256 uints (512 k fp16) + pad 4
    __shared__ unsigned ws_[32][260];
    const int t = threadIdx.x;
    const int b0 = blockIdx.x * 32;
    const int o0 = blockIdx.y * 32;
    const unsigned* hu = reinterpret_cast<const unsigned*>(hh);
    const unsigned* wu = reinterpret_cast<const unsigned*>(wh);

    // stage all 512 k: 2048 uint4 per array, 4 per thread, coalesced global reads
    #pragma unroll
    for (int r = 0; r < 4; ++r) {
        const int s = t + r * 512;
        const int row = s >> 6;          // 0..31
        const int c16 = s & 63;          // uint4 col
        *reinterpret_cast<uint4*>(&hs[row][c16 * 4]) =
            *reinterpret_cast<const uint4*>(&hu[(size_t)(b0 + row) * 256 + c16 * 4]);
        *reinterpret_cast<uint4*>(&ws_[row][c16 * 4]) =
            *reinterpret_cast<const uint4*>(&wu[(size_t)(o0 + row) * 256 + c16 * 4]);
    }
    __syncthreads();

    const int ks = t >> 7;               // k-quarter 0..3 (wave-uniform)
    const int ts = t & 127;
    const int bi = ts >> 4;              // 0..7
    const int oj = ts & 15;              // 0..15

    half2v acc[4][2] = {};

    const int base = ks * 64;
    #pragma unroll 2
    for (int g = 0; g < 16; ++g) {
        const int col = base + g * 4;
        uint4 hv[4], wv[2];
        #pragma unroll
        for (int c = 0; c < 4; ++c)
            hv[c] = *reinterpret_cast<const uint4*>(&hs[bi + 8 * c][col]);
        #pragma unroll
        for (int d = 0; d < 2; ++d)
            wv[d] = *reinterpret_cast<const uint4*>(&ws_[oj + 16 * d][col]);
        #pragma unroll
        for (int c = 0; c < 4; ++c) {
            #pragma unroll
            for (int d = 0; d < 2; ++d) {
                canb2(hv[c].x, wv[d].x, acc[c][d]);
                canb2(hv[c].y, wv[d].y, acc[c][d]);
                canb2(hv[c].z, wv[d].z, acc[c][d]);
                canb2(hv[c].w, wv[d].w, acc[c][d]);
            }
        }
    }

    float p[8];
    #pragma unroll
    for (int c = 0; c < 4; ++c)
        #pragma unroll
        for (int d = 0; d < 2; ++d)
            p[c * 2 + d] = (float)acc[c][d].x + (float)acc[c][d].y;

    // 4-way k-reduce in LDS (reuse hs after barrier)
    __syncthreads();
    float* red = reinterpret_cast<float*>(&hs[0][0]);   // 3*128*8 = 3072 floats = 12KB
    if (ks > 0) {
        float* rp = &red[((size_t)(ks - 1) * 128 + ts) * 8];
        #pragma unroll
        for (int i = 0; i < 8; ++i) rp[i] = p[i];
    }
    __syncthreads();
    if (ks == 0) {
        #pragma unroll
        for (int q = 0; q < 3; ++q) {
            const float* rp = &red[((size_t)q * 128 + ts) * 8];
            #pragma unroll
            for (int i = 0; i < 8; ++i) p[i] += rp[i];
        }
        #pragma unroll
        for (int c = 0; c < 4; ++c) {
            #pragma unroll
            for (int d = 0; d < 2; ++d) {
                float dd = 512.0f - 2.0f * p[c * 2 + d] + EPSF;
                dd = fminf(fmaxf(dd, EPSF), 1000000.0f);
                out[(size_t)(b0 + bi + 8 * c) * OUT_SZ + o0 + oj + 16 * d] = 1.0f / dd;
            }
        }
    }
}

extern "C" void kernel_launch(void* const* d_in, const int* in_sizes, int n_in,
                              void* d_out, int out_size, void* d_ws, size_t ws_size,
                              hipStream_t stream) {
    const float* x  = (const float*)d_in[0];
    const float* W1 = (const float*)d_in[1];
    const float* b1 = (const float*)d_in[2];
    const float* Wd = (const float*)d_in[3];
    float* out = (float*)d_out;
    unsigned short* hh = (unsigned short*)d_ws;                          // 1 MB fp16 h
    unsigned short* wh = (unsigned short*)((char*)d_ws + (1u << 20));    // 0.5 MB fp16 relu(Wd)

    gemm_mfma<<<dim3(32, 16), 256, 0, stream>>>(x, W1, b1, Wd, hh, wh);
    canberra4<<<dim3(32, 16), 512, 0, stream>>>(hh, wh, out);
}